// Round 3
// baseline (555.680 us; speedup 1.0000x reference)
//
#include <hip/hip_runtime.h>
#include <hip/hip_bf16.h>
#include <stdint.h>

// R5: gemm_qk rewritten as 256x256 / BK=64 / 8-wave, 8-phase counted-vmcnt
// pipeline (T2+T3+T4+T5). Ring of 8 x 16KB half-tiles ([256][32] bf16, A/B x
// k-half); each phase: ds_read frags + stage 1 half (2 global_load_lds, +6
// phases ahead) + barrier + 16 MFMA + (odd phases) vmcnt(8) + barrier.
// vmcnt never drains to 0 in-loop. LDS XOR swizzle col^=(row&3) applied on
// BOTH sides (pre-swizzled global src, swizzled ds_read) per rule 21.
// gemm_bt / attn2 / convert_x / prep unchanged (verified). R3 swizzle kept.

typedef __attribute__((ext_vector_type(8))) short short8;
typedef __attribute__((ext_vector_type(4))) float f32x4;
typedef __attribute__((ext_vector_type(4))) unsigned int u32x4;

#define GPTR(p) ((const __attribute__((address_space(1))) void*)(p))
#define SPTR(p) ((__attribute__((address_space(3))) void*)(p))

__device__ __forceinline__ float b2f(unsigned short h) {
  union { unsigned u; float f; } c; c.u = ((unsigned)h) << 16; return c.f;
}
__device__ __forceinline__ unsigned short f2b(float f) {
  union { float f; unsigned u; } c; c.f = f;
  unsigned u = c.u;
  return (unsigned short)((u + 0x7fffu + ((u >> 16) & 1u)) >> 16);
}

__device__ __forceinline__ bool get_mask(const void* p, int b) {
  const unsigned* u = (const unsigned*)p;
  unsigned v0 = u[0], v1 = u[1];
  if (v0 <= 1u && v1 <= 1u) return (b ? v1 : v0) != 0u;
  const unsigned char* c = (const unsigned char*)p;
  return c[b] != 0;
}

// ---------------- prep ------------------------------------------------------
__global__ __launch_bounds__(256) void prep(
    const float* __restrict__ wq, const float* __restrict__ wkv,
    const float* __restrict__ wout, const float* __restrict__ invf,
    unsigned short* __restrict__ W1t, unsigned short* __restrict__ W2t,
    float* __restrict__ cos_t, float* __restrict__ sin_t) {
  const int tid = blockIdx.x * 256 + threadIdx.x;
  if (tid < 1536 * 512) {
    const int j = tid >> 9, kk = tid & 511;
    float v = (j < 512) ? wq[kk * 512 + j] * 0.125f : wkv[kk * 1024 + (j - 512)];
    W1t[tid] = f2b(v);
  }
  if (tid < 512 * 512) {
    const int j = tid >> 9, kk = tid & 511;
    W2t[tid] = f2b(wout[kk * 512 + j]);
  }
  if (tid < 1024) {
    const int i = tid >> 5, p = tid & 31;
    const float f = (float)i * invf[p];
    cos_t[tid] = cosf(f);
    sin_t[tid] = sinf(f);
  }
}

// ---------------- convert x fp32 -> bf16 ------------------------------------
__global__ __launch_bounds__(256) void convert_x(const float* __restrict__ x,
                                                 unsigned short* __restrict__ xb) {
  const int i = (blockIdx.x * 256 + threadIdx.x) * 8;
  const float4 a = *(const float4*)(x + i);
  const float4 b = *(const float4*)(x + i + 4);
  union { unsigned short us[8]; u32x4 v; } o;
  o.us[0] = f2b(a.x); o.us[1] = f2b(a.y); o.us[2] = f2b(a.z); o.us[3] = f2b(a.w);
  o.us[4] = f2b(b.x); o.us[5] = f2b(b.y); o.us[6] = f2b(b.z); o.us[7] = f2b(b.w);
  *(u32x4*)(xb + i) = o.v;
}

// ---------------- generic GEMM (m97 recipe, verified) -----------------------
template <int OUT_MODE>
__global__ __launch_bounds__(256, 2) void gemm_bt(
    const unsigned short* __restrict__ A, const unsigned short* __restrict__ Bt,
    void* __restrict__ Cout, int M, int N, int K) {
  __shared__ __align__(16) unsigned short smem[17408];
  unsigned short* As = smem;
  unsigned short* Bs = smem + 8192;

  const int nb = N >> 7;
  const int cpx = gridDim.x >> 3;
  const int bid = (blockIdx.x & 7) * cpx + (blockIdx.x >> 3);
  const int bm = bid / nb, bn = bid % nb;
  const int t = threadIdx.x, lane = t & 63, w = t >> 6;
  const int wm = (w >> 1) << 6, wn = (w & 1) << 6;

  f32x4 acc[4][4] = {};

  const size_t Ks = (size_t)K;
  const unsigned short* gA = A + (size_t)(bm * 128 + w * 32 + (lane >> 3)) * Ks + ((lane & 7) << 3);
  const unsigned short* gB = Bt + (size_t)(bn * 128 + w * 32 + (lane >> 3)) * Ks + ((lane & 7) << 3);
  unsigned short* lA = As + w * 32 * 64;
  unsigned short* lB = Bs + w * 32 * 64;

  for (int k0 = 0; k0 < K; k0 += 64) {
#pragma unroll
    for (int i = 0; i < 4; ++i) {
      __builtin_amdgcn_global_load_lds(GPTR(gA + (size_t)i * 8 * Ks), SPTR(lA + i * 512), 16, 0, 0);
      __builtin_amdgcn_global_load_lds(GPTR(gB + (size_t)i * 8 * Ks), SPTR(lB + i * 512), 16, 0, 0);
    }
    gA += 64; gB += 64;
    __syncthreads();
#pragma unroll
    for (int ks = 0; ks < 2; ++ks) {
      const int kr = (ks << 5) + ((lane >> 4) << 3);
      const int r = lane & 15;
      short8 af[4], bf[4];
#pragma unroll
      for (int x = 0; x < 4; ++x) af[x] = *(const short8*)(As + (wm + (x << 4) + r) * 64 + kr);
#pragma unroll
      for (int x = 0; x < 4; ++x) bf[x] = *(const short8*)(Bs + (wn + (x << 4) + r) * 64 + kr);
#pragma unroll
      for (int xm = 0; xm < 4; ++xm)
#pragma unroll
        for (int xn = 0; xn < 4; ++xn)
          acc[xm][xn] = __builtin_amdgcn_mfma_f32_16x16x32_bf16(af[xm], bf[xn], acc[xm][xn], 0, 0, 0);
    }
    __syncthreads();
  }

  if (OUT_MODE == 0) {
    unsigned short* Ct = smem;
    const int cb = wn + (lane & 15);
    const int rb = wm + ((lane >> 4) << 2);
#pragma unroll
    for (int xn = 0; xn < 4; ++xn)
#pragma unroll
      for (int xm = 0; xm < 4; ++xm) {
        const f32x4 v = acc[xm][xn];
        unsigned long long pk = (unsigned long long)f2b(v[0]) |
                                ((unsigned long long)f2b(v[1]) << 16) |
                                ((unsigned long long)f2b(v[2]) << 32) |
                                ((unsigned long long)f2b(v[3]) << 48);
        *(unsigned long long*)(Ct + (size_t)(cb + (xn << 4)) * 136 + rb + (xm << 4)) = pk;
      }
    __syncthreads();
    unsigned short* Cg = (unsigned short*)Cout;
#pragma unroll
    for (int it = 0; it < 8; ++it) {
      const int idx = it * 256 + t;
      const int c = idx >> 4;
      const int rc = (idx & 15) << 3;
      const u32x4 val = *(const u32x4*)(Ct + c * 136 + rc);
      *(u32x4*)(Cg + (size_t)(bn * 128 + c) * (size_t)M + (size_t)bm * 128 + rc) = val;
    }
  } else {
    float* Cg = (float*)Cout;
    const int cb = bn * 128 + wn + (lane & 15);
    const int rb = bm * 128 + wm + ((lane >> 4) << 2);
#pragma unroll
    for (int xm = 0; xm < 4; ++xm)
#pragma unroll
      for (int xn = 0; xn < 4; ++xn)
#pragma unroll
        for (int u = 0; u < 4; ++u)
          Cg[(size_t)(rb + (xm << 4) + u) * (size_t)N + cb + (xn << 4)] = acc[xm][xn][u];
  }
}

// ---------------- 256^2 8-phase q/k GEMM ------------------------------------
// Ring slot s holds half-tile H (H&7==s): H = 4*T + j, j: 0=A k0, 1=B k0,
// 2=A k1, 3=B k1 of K-tile T (BK=64, k-half=32 cols). Slot = [256][32] bf16,
// 16 KB, 64 B rows, XOR swizzle: element (row, chunk l4) stored at chunk
// l4 ^ (row&3). Stage = 2 global_load_lds per thread (wave covers 32 rows).
// Phase P = 4T + wq: wq={0:mt0-3/k0, 1:mt4-7/k0, 2:mt0-3/k1, 3:mt4-7/k1};
// stages half H=P+6 (ledger: every half >=5 phases old at first read; every
// slot overwritten >=1 barrier after its last reader); vmcnt(8) at odd wq
// guarantees the next 2 phases' halves (4 newer halves = 8 loads in flight).
template <int TT, int WQ, int SSLOT, int SMAT, bool DOSTG, int VMN>
__device__ __forceinline__ void phase256(
    const unsigned short* __restrict__ gA, const unsigned short* __restrict__ gB,
    unsigned short (&ring)[8][256][32], f32x4 (&acc)[8][4], short8 (&bf)[4],
    int w, int wm, int wn, int l15, int l4, int koff) {
  constexpr int KH = WQ >> 1;
  constexpr int G = WQ & 1;
  constexpr int SA = TT * 4 + KH * 2;
  constexpr int SB = SA + 1;
  short8 af[4];
#pragma unroll
  for (int x = 0; x < 4; ++x) {
    const int row = wm * 128 + (G * 4 + x) * 16 + l15;
    af[x] = *(const short8*)(&ring[SA][row][(l4 ^ (row & 3)) << 3]);
  }
  if constexpr (G == 0) {
#pragma unroll
    for (int x = 0; x < 4; ++x) {
      const int row = wn * 64 + x * 16 + l15;
      bf[x] = *(const short8*)(&ring[SB][row][(l4 ^ (row & 3)) << 3]);
    }
  }
  if constexpr (DOSTG) {
    const unsigned short* src = (SMAT ? gB : gA) + koff;
#pragma unroll
    for (int i = 0; i < 2; ++i)
      __builtin_amdgcn_global_load_lds(GPTR(src + (size_t)i * 16 * 512),
                                       SPTR(&ring[SSLOT][w * 32 + i * 16][0]), 16, 0, 0);
  }
  __builtin_amdgcn_s_barrier();
  asm volatile("" ::: "memory");
  __builtin_amdgcn_s_setprio(1);
#pragma unroll
  for (int x = 0; x < 4; ++x)
#pragma unroll
    for (int n = 0; n < 4; ++n)
      acc[G * 4 + x][n] =
          __builtin_amdgcn_mfma_f32_16x16x32_bf16(bf[n], af[x], acc[G * 4 + x][n], 0, 0, 0);
  __builtin_amdgcn_s_setprio(0);
  if constexpr (VMN == 8) asm volatile("s_waitcnt vmcnt(8)" ::: "memory");
  if constexpr (VMN == 4) asm volatile("s_waitcnt vmcnt(4)" ::: "memory");
  if constexpr (VMN == 0) asm volatile("s_waitcnt vmcnt(0)" ::: "memory");
  __builtin_amdgcn_s_barrier();
  asm volatile("" ::: "memory");
}

__global__ __launch_bounds__(512, 2) void gemm_qk256(
    const unsigned short* __restrict__ A,   // xb [65536][512] bf16
    const unsigned short* __restrict__ Bt,  // W1t rows 0..1023 (q|k features)
    unsigned short* __restrict__ qkout,     // [65536][1024] bf16 token-major
    const float* __restrict__ cos_t, const float* __restrict__ sin_t) {
  __shared__ __align__(16) unsigned short ring[8][256][32];  // 131072 B

  // XCD swizzle: grid 1024 %8==0; each XCD gets 32 bm x all 4 bn.
  const int bid = ((blockIdx.x & 7) << 7) + (blockIdx.x >> 3);
  const int bm = bid >> 2, bn = bid & 3;
  const int t = threadIdx.x, lane = t & 63, w = t >> 6;
  const int wm = w >> 2, wn = w & 3;  // 2x4 wave grid; wave tile 128x64
  const int l15 = lane & 15, l4 = lane >> 4;

  // stage source (pre-swizzled chunk so linear LDS write == swizzled layout)
  const int swz = ((lane & 3) ^ ((lane >> 2) & 3)) << 3;
  const unsigned short* gA = A + (size_t)(bm * 256 + w * 32 + (lane >> 2)) * 512 + swz;
  const unsigned short* gB = Bt + (size_t)(bn * 256 + w * 32 + (lane >> 2)) * 512 + swz;

  f32x4 acc[8][4] = {};  // swapped-op: lane holds token=col(l15), feature=row(l4*4+r)
  short8 bf[4];

  // prologue: stage halves 0..5 (slots 0..5), wait oldest 2 (slots 0,1 landed)
#pragma unroll
  for (int h = 0; h < 6; ++h) {
    const unsigned short* src = ((h & 1) ? gB : gA) + (h >> 1) * 32;
#pragma unroll
    for (int i = 0; i < 2; ++i)
      __builtin_amdgcn_global_load_lds(GPTR(src + (size_t)i * 16 * 512),
                                       SPTR(&ring[h][w * 32 + i * 16][0]), 16, 0, 0);
  }
  asm volatile("s_waitcnt vmcnt(8)" ::: "memory");
  __builtin_amdgcn_s_barrier();
  asm volatile("" ::: "memory");

  for (int it = 0; it < 3; ++it) {
    const int kb = it * 128;
    phase256<0, 0, 6, 0, true, -1>(gA, gB, ring, acc, bf, w, wm, wn, l15, l4, kb + 96);
    phase256<0, 1, 7, 1, true, 8>(gA, gB, ring, acc, bf, w, wm, wn, l15, l4, kb + 96);
    phase256<0, 2, 0, 0, true, -1>(gA, gB, ring, acc, bf, w, wm, wn, l15, l4, kb + 128);
    phase256<0, 3, 1, 1, true, 8>(gA, gB, ring, acc, bf, w, wm, wn, l15, l4, kb + 128);
    phase256<1, 0, 2, 0, true, -1>(gA, gB, ring, acc, bf, w, wm, wn, l15, l4, kb + 160);
    phase256<1, 1, 3, 1, true, 8>(gA, gB, ring, acc, bf, w, wm, wn, l15, l4, kb + 160);
    phase256<1, 2, 4, 0, true, -1>(gA, gB, ring, acc, bf, w, wm, wn, l15, l4, kb + 192);
    phase256<1, 3, 5, 1, true, 8>(gA, gB, ring, acc, bf, w, wm, wn, l15, l4, kb + 192);
  }
  // peeled last iteration (tiles 6,7): stage only first 2 phases; drain waits
  phase256<0, 0, 6, 0, true, -1>(gA, gB, ring, acc, bf, w, wm, wn, l15, l4, 480);
  phase256<0, 1, 7, 1, true, 8>(gA, gB, ring, acc, bf, w, wm, wn, l15, l4, 480);
  phase256<0, 2, 0, 0, false, -1>(gA, gB, ring, acc, bf, w, wm, wn, l15, l4, 0);
  phase256<0, 3, 1, 1, false, 4>(gA, gB, ring, acc, bf, w, wm, wn, l15, l4, 0);
  phase256<1, 0, 2, 0, false, -1>(gA, gB, ring, acc, bf, w, wm, wn, l15, l4, 0);
  phase256<1, 1, 3, 1, false, 0>(gA, gB, ring, acc, bf, w, wm, wn, l15, l4, 0);
  phase256<1, 2, 4, 0, false, -1>(gA, gB, ring, acc, bf, w, wm, wn, l15, l4, 0);
  phase256<1, 3, 5, 1, false, -1>(gA, gB, ring, acc, bf, w, wm, wn, l15, l4, 0);

  // Epilogue: RoPE (f32) -> bf16 -> LDS transpose (2 col-half passes) -> store
  unsigned short* Ct = &ring[0][0][0];  // [tok 256][stride 132]
#pragma unroll
  for (int p = 0; p < 2; ++p) {
    if ((wn >> 1) == p) {
#pragma unroll
      for (int mt = 0; mt < 8; ++mt) {
        const int t_loc = wm * 128 + mt * 16 + l15;
        const int pos = t_loc & 31;  // bm*256 is 32-aligned
#pragma unroll
        for (int nt = 0; nt < 4; ++nt) {
          const int f_loc = wn * 64 + nt * 16 + (l4 << 2);
          const int p0 = (f_loc >> 1) & 31;  // even; p0+1 <= 31
          const float c0 = cos_t[pos * 32 + p0], s0 = sin_t[pos * 32 + p0];
          const float c1 = cos_t[pos * 32 + p0 + 1], s1 = sin_t[pos * 32 + p0 + 1];
          const f32x4 v = acc[mt][nt];
          const float o0 = v[0] * c0 - v[1] * s0;
          const float o1 = v[1] * c0 + v[0] * s0;
          const float o2 = v[2] * c1 - v[3] * s1;
          const float o3 = v[3] * c1 + v[2] * s1;
          unsigned long long pk = (unsigned long long)f2b(o0) |
                                  ((unsigned long long)f2b(o1) << 16) |
                                  ((unsigned long long)f2b(o2) << 32) |
                                  ((unsigned long long)f2b(o3) << 48);
          const int c_loc = (wn & 1) * 64 + nt * 16 + (l4 << 2);
          *(unsigned long long*)(Ct + (size_t)t_loc * 132 + c_loc) = pk;
        }
      }
    }
    __syncthreads();
#pragma unroll
    for (int itst = 0; itst < 8; ++itst) {
      const int idx = itst * 512 + t;
      const int row = idx >> 4;
      const int c8 = (idx & 15) << 3;
      const u32x4 val = *(const u32x4*)(Ct + row * 132 + c8);
      *(u32x4*)(qkout + (size_t)(bm * 256 + row) * 1024 + bn * 256 + p * 128 + c8) = val;
    }
    __syncthreads();
  }
}

// ---------------- attention (verified) --------------------------------------
__global__ __launch_bounds__(256) void attn2(
    const unsigned short* __restrict__ qk,
    const unsigned short* __restrict__ vbuf,
    const float* __restrict__ pos_bias,
    const void* __restrict__ maskp,
    unsigned short* __restrict__ attn_out) {
  const int wv = threadIdx.x >> 6;
  const int lane = threadIdx.x & 63;
  const int unit = blockIdx.x * 4 + wv;
  const int bs = unit >> 3, h = unit & 7;
  const int row0 = bs << 5;
  const int l15 = lane & 15, l4 = lane >> 4;

  __shared__ __align__(16) char lds[4 * 6656];
  char* wb = lds + wv * 6656;
  float* S = (float*)wb;
  unsigned short* Olds = (unsigned short*)wb;
  unsigned short* Pp = (unsigned short*)(wb + 4608);

  const unsigned short* qb = qk + (size_t)row0 * 1024 + h * 64;
  short8 qf[2][2], kf[2][2];
#pragma unroll
  for (int ti = 0; ti < 2; ++ti)
#pragma unroll
    for (int ks = 0; ks < 2; ++ks) {
      const size_t off = (size_t)((ti << 4) + l15) * 1024 + (ks << 5) + (l4 << 3);
      qf[ti][ks] = *(const short8*)(qb + off);
      kf[ti][ks] = *(const short8*)(qb + 512 + off);
    }
  f32x4 sc[2][2];
#pragma unroll
  for (int ti = 0; ti < 2; ++ti)
#pragma unroll
    for (int tj = 0; tj < 2; ++tj) {
      f32x4 z = {0.f, 0.f, 0.f, 0.f};
      z = __builtin_amdgcn_mfma_f32_16x16x32_bf16(qf[ti][0], kf[tj][0], z, 0, 0, 0);
      sc[ti][tj] = __builtin_amdgcn_mfma_f32_16x16x32_bf16(qf[ti][1], kf[tj][1], z, 0, 0, 0);
    }
#pragma unroll
  for (int ti = 0; ti < 2; ++ti)
#pragma unroll
    for (int tj = 0; tj < 2; ++tj)
#pragma unroll
      for (int r = 0; r < 4; ++r)
        S[((ti << 4) + (l4 << 2) + r) * 36 + (tj << 4) + l15] = sc[ti][tj][r];
  __syncthreads();

  {
    const int i = lane & 31;
    const int c = lane >> 5;
    const bool fm = get_mask(maskp, bs >> 10);
    float v[16];
    const float* Sr = S + i * 36 + (c << 4);
    const float* bp = pos_bias + h * 1024 + i * 32 + (c << 4);
#pragma unroll
    for (int g = 0; g < 4; ++g) {
      const float4 sv = *(const float4*)(Sr + (g << 2));
      const float4 bv = *(const float4*)(bp + (g << 2));
      v[g * 4 + 0] = sv.x + bv.x; v[g * 4 + 1] = sv.y + bv.y;
      v[g * 4 + 2] = sv.z + bv.z; v[g * 4 + 3] = sv.w + bv.w;
    }
    float m = v[0];
#pragma unroll
    for (int j = 1; j < 16; ++j) m = fmaxf(m, v[j]);
    m = fmaxf(m, __shfl_xor(m, 32, 64));
    float sum = 0.f;
#pragma unroll
    for (int j = 0; j < 16; ++j) { v[j] = __expf(v[j] - m); sum += v[j]; }
    sum += __shfl_xor(sum, 32, 64);
    const float inv = 1.f / sum;
    union { unsigned short us[8]; u32x4 u; } w0, w1;
    if (fm) {
#pragma unroll
      for (int j = 0; j < 8; ++j) {
        w0.us[j] = (((c << 4) + j) == i) ? (unsigned short)0x3F80 : (unsigned short)0;
        w1.us[j] = (((c << 4) + 8 + j) == i) ? (unsigned short)0x3F80 : (unsigned short)0;
      }
    } else {
#pragma unroll
      for (int j = 0; j < 8; ++j) {
        w0.us[j] = f2b(v[j] * inv);
        w1.us[j] = f2b(v[8 + j] * inv);
      }
    }
    const int ti = i >> 4, i15 = i & 15;
    *(u32x4*)(Pp + (size_t)((ti << 6) + ((2 * c + 0) << 4) + i15) * 8) = w0.u;
    *(u32x4*)(Pp + (size_t)((ti << 6) + ((2 * c + 1) << 4) + i15) * 8) = w1.u;
  }
  __syncthreads();

  short8 pf[2];
#pragma unroll
  for (int ti = 0; ti < 2; ++ti) pf[ti] = *(const short8*)(Pp + (size_t)((ti << 6) + lane) * 8);
  short8 vf[4];
#pragma unroll
  for (int td = 0; td < 4; ++td)
    vf[td] = *(const short8*)(vbuf + (size_t)(h * 64 + (td << 4) + l15) * 65536 + row0 + (l4 << 3));
  f32x4 o[2][4];
#pragma unroll
  for (int ti = 0; ti < 2; ++ti)
#pragma unroll
    for (int td = 0; td < 4; ++td) {
      f32x4 z = {0.f, 0.f, 0.f, 0.f};
      o[ti][td] = __builtin_amdgcn_mfma_f32_16x16x32_bf16(pf[ti], vf[td], z, 0, 0, 0);
    }
  __syncthreads();

#pragma unroll
  for (int ti = 0; ti < 2; ++ti)
#pragma unroll
    for (int td = 0; td < 4; ++td)
#pragma unroll
      for (int r = 0; r < 4; ++r)
        Olds[((ti << 4) + (l4 << 2) + r) * 72 + (td << 4) + l15] = f2b(o[ti][td][r]);
  __syncthreads();
#pragma unroll
  for (int p = 0; p < 4; ++p) {
    const int idx = (p << 6) + lane;
    const int i = idx >> 3;
    const int ch = (idx & 7) << 3;
    const u32x4 val = *(const u32x4*)(Olds + i * 72 + ch);
    *(u32x4*)(attn_out + (size_t)(row0 + i) * 512 + h * 64 + ch) = val;
  }
}

// ---------------- launch ----------------------------------------------------
extern "C" void kernel_launch(void* const* d_in, const int* in_sizes, int n_in,
                              void* d_out, int out_size, void* d_ws, size_t ws_size,
                              hipStream_t stream) {
  const float* x = (const float*)d_in[0];
  const float* pos_bias = (const float*)d_in[1];
  const void* maskp = d_in[2];
  const float* wq = (const float*)d_in[3];
  const float* wkv = (const float*)d_in[4];
  const float* wout = (const float*)d_in[5];
  const float* invf = (const float*)d_in[6];

  char* ws = (char*)d_ws;
  unsigned short* xb = (unsigned short*)(ws);
  unsigned short* qkbuf = (unsigned short*)(ws + 67108864);
  unsigned short* vbuf = (unsigned short*)(ws + 201326592);
  unsigned short* W1t = (unsigned short*)(ws + 268435456);
  unsigned short* W2t = (unsigned short*)(ws + 270008320);
  float* cos_t = (float*)(ws + 270532608);
  float* sin_t = (float*)(ws + 270536704);

  prep<<<3072, 256, 0, stream>>>(wq, wkv, wout, invf, W1t, W2t, cos_t, sin_t);
  convert_x<<<16384, 256, 0, stream>>>(x, xb);
  gemm_qk256<<<1024, 512, 0, stream>>>(xb, W1t, qkbuf, cos_t, sin_t);
  gemm_bt<0><<<2048, 256, 0, stream>>>(xb, W1t + (size_t)1024 * 512, (void*)vbuf, 65536, 512, 512);
  attn2<<<4096, 256, 0, stream>>>(qkbuf, vbuf, pos_bias, maskp, xb);
  gemm_bt<1><<<2048, 256, 0, stream>>>(xb, W2t, d_out, 65536, 512, 512);
}